// Round 9
// baseline (695.851 us; speedup 1.0000x reference)
//
#include <hip/hip_runtime.h>
#include <hip/hip_fp16.h>
#include <stdint.h>

// ---------------- problem constants ----------------
#define NODES 50000
#define F_IN 128
#define F_H1 256
#define F_H2 256
#define F_OUT 64
#define SLICES 64            // edge slices for hist/scatter
#define NPACK (NODES / 2)    // packed ushort-pair bins (25000)
#define HPACK (NPACK / 2)    // bins per node-half block (12500, 50 KB LDS)
#define SPMM_J 128           // blocks per XCD for sliced SpMM (grid = 8*J)

using f32x4    = __attribute__((ext_vector_type(4))) float;
using f16x8    = __attribute__((ext_vector_type(8))) _Float16;   // 8 fp16 in 4 VGPRs
using ushort8v = __attribute__((ext_vector_type(8))) unsigned short;

// ---------------- atomic-free degree/CSR machinery ----------------
__global__ __launch_bounds__(512) void k_hist(
    const int* __restrict__ src, const int* __restrict__ dst,
    unsigned* __restrict__ p_out, unsigned* __restrict__ p_in, int e) {
  __shared__ unsigned bins[HPACK];
  const int s = blockIdx.x >> 1;
  const int r = blockIdx.x & 1;
  const int nlo = r * (NODES / 2);
  const int nhi = nlo + NODES / 2;
  const int plo = r * HPACK;
  const int per = (e + SLICES - 1) / SLICES;
  const int beg = s * per;
  const int end = min(e, beg + per);

  for (int j = threadIdx.x; j < HPACK; j += 512) bins[j] = 0;
  __syncthreads();
  for (int i = beg + (int)threadIdx.x; i < end; i += 512) {
    int a = src[i];
    if (a >= nlo && a < nhi)
      atomicAdd(&bins[(a >> 1) - plo], 1u << ((a & 1) << 4));
  }
  __syncthreads();
  for (int j = threadIdx.x; j < HPACK; j += 512)
    p_out[(size_t)s * NPACK + plo + j] = bins[j];
  __syncthreads();

  for (int j = threadIdx.x; j < HPACK; j += 512) bins[j] = 0;
  __syncthreads();
  for (int i = beg + (int)threadIdx.x; i < end; i += 512) {
    int d = dst[i];
    if (d >= nlo && d < nhi)
      atomicAdd(&bins[(d >> 1) - plo], 1u << ((d & 1) << 4));
  }
  __syncthreads();
  for (int j = threadIdx.x; j < HPACK; j += 512)
    p_in[(size_t)s * NPACK + plo + j] = bins[j];
}

__global__ __launch_bounds__(256) void k_degnorm(
    const unsigned* __restrict__ p_out, const unsigned* __restrict__ p_in,
    unsigned* __restrict__ base_in, int* __restrict__ deg_in,
    float* __restrict__ ns, float* __restrict__ nd) {
  int p = blockIdx.x * 256 + threadIdx.x;
  if (p >= NPACK) return;
  unsigned so = 0, si = 0;
#pragma unroll 4
  for (int s = 0; s < SLICES; ++s) {
    so += p_out[(size_t)s * NPACK + p];
    unsigned vi = p_in[(size_t)s * NPACK + p];
    base_in[(size_t)s * NPACK + p] = si;   // exclusive prefix across slices
    si += vi;
  }
  int o0 = (int)(so & 0xFFFFu) + 1, o1 = (int)(so >> 16) + 1;   // +1 self-loop
  int i0 = (int)(si & 0xFFFFu) + 1, i1 = (int)(si >> 16) + 1;
  int n0 = p * 2, n1 = n0 + 1;
  deg_in[n0] = i0; deg_in[n1] = i1;
  ns[n0] = rsqrtf((float)o0); ns[n1] = rsqrtf((float)o1);
  nd[n0] = rsqrtf((float)i0); nd[n1] = rsqrtf((float)i1);
}

// ---------------- parallel 3-phase exclusive scan over (deg_in - 1) ----------------
__global__ __launch_bounds__(256) void k_scan1(const int* __restrict__ deg_in,
                                               int* __restrict__ psum, int n) {
  int i = blockIdx.x * 256 + threadIdx.x;
  int v = (i < n) ? deg_in[i] - 1 : 0;
#pragma unroll
  for (int o = 1; o < 64; o <<= 1) v += __shfl_xor(v, o);
  __shared__ int ws[4];
  if ((threadIdx.x & 63) == 0) ws[threadIdx.x >> 6] = v;
  __syncthreads();
  if (threadIdx.x == 0) psum[blockIdx.x] = ws[0] + ws[1] + ws[2] + ws[3];
}

__global__ __launch_bounds__(256) void k_scan2(int* __restrict__ psum, int nb) {
  __shared__ int s[256];
  int t = threadIdx.x;
  int v = (t < nb) ? psum[t] : 0;
  s[t] = v;
  __syncthreads();
  for (int o = 1; o < 256; o <<= 1) {
    int u = (t >= o) ? s[t - o] : 0;
    __syncthreads();
    s[t] += u;
    __syncthreads();
  }
  if (t < nb) psum[t] = s[t] - v;   // exclusive
}

__global__ __launch_bounds__(256) void k_scan3(const int* __restrict__ deg_in,
                                               const int* __restrict__ psum,
                                               int* __restrict__ row_ptr, int n) {
  int i = blockIdx.x * 256 + threadIdx.x;
  int lane = threadIdx.x & 63;
  int w = threadIdx.x >> 6;
  int v = (i < n) ? deg_in[i] - 1 : 0;
  int x = v;
#pragma unroll
  for (int o = 1; o < 64; o <<= 1) {
    int u = __shfl_up(x, o);
    if (lane >= o) x += u;
  }
  __shared__ int wsum[4];
  if (lane == 63) wsum[w] = x;
  __syncthreads();
  int woff = 0;
#pragma unroll
  for (int j = 0; j < 4; ++j)
    if (j < w) woff += wsum[j];
  int excl = x - v + woff + psum[blockIdx.x];
  if (i < n) row_ptr[i] = excl;
  if (i == n - 1) row_ptr[n] = excl + v;
}

__global__ __launch_bounds__(512) void k_scatter2(
    const int* __restrict__ src, const int* __restrict__ dst,
    const int* __restrict__ row_ptr, const unsigned* __restrict__ base_in,
    int* __restrict__ csr_src, int e) {
  __shared__ unsigned cur[HPACK];
  const int s = blockIdx.x >> 1;
  const int r = blockIdx.x & 1;
  const int nlo = r * (NODES / 2);
  const int nhi = nlo + NODES / 2;
  const int plo = r * HPACK;
  const int per = (e + SLICES - 1) / SLICES;
  const int beg = s * per;
  const int end = min(e, beg + per);
  for (int j = threadIdx.x; j < HPACK; j += 512)
    cur[j] = base_in[(size_t)s * NPACK + plo + j];
  __syncthreads();
  for (int i = beg + (int)threadIdx.x; i < end; i += 512) {
    int d = dst[i];
    if (d >= nlo && d < nhi) {
      int sh = (d & 1) << 4;
      unsigned old = atomicAdd(&cur[(d >> 1) - plo], 1u << sh);
      int local = (int)((old >> sh) & 0xFFFFu);
      csr_src[row_ptr[d] + local] = src[i];
    }
  }
}

// ---------------- feats prescale -> fp16: Y = fp16(ns[row] * X), X:[n][128] ----------------
__global__ void k_prescale_h(const float* __restrict__ X, const float* __restrict__ ns,
                             __half* __restrict__ Y, int total4) {
  int i = blockIdx.x * blockDim.x + threadIdx.x;
  if (i < total4) {
    int row = i >> 5;                       // 32 float4 per 128-col row
    float s = ns[row];
    float4 v = reinterpret_cast<const float4*>(X)[i];
    __half2 h0 = __floats2half2_rn(v.x * s, v.y * s);
    __half2 h1 = __floats2half2_rn(v.z * s, v.w * s);
    union { struct { __half2 a, b; } h; uint2 u; } o;
    o.h.a = h0; o.h.b = h1;
    reinterpret_cast<uint2*>(Y)[i] = o.u;
  }
}

// ---------------- weight prep: W[K][NOUT] f32 -> Wt [NOUT][K] fp16 ----------------
__global__ void k_wprep_h(const float* __restrict__ W, __half* __restrict__ Wt,
                          int K, int NOUT) {
  int i = blockIdx.x * blockDim.x + threadIdx.x;
  if (i < K * NOUT) {
    int k = i / NOUT, n = i % NOUT;
    Wt[(size_t)n * K + k] = __float2half_rn(W[i]);
  }
}

// ---------------- XCD-sliced SpMM ----------------
// Y[v] = nd[v]*(X[v] + sum_{u->v} X[u]) (+bias).  Feature dim split into
// D/32 slices of 32 cols (3.2 MB fp16 @ N=50000 -> fits one XCD's 4 MB L2).
// blockIdx%8 round-robins XCDs (m09): XCD x owns slice x%NSL and node group
// x/NSL -> after cold fill every gather is an L2 hit on that XCD.
// Wave: 4 edges/iter x 16 lanes/row x 4B; butterfly combine over edge slots.
template <int D, bool BIAS, bool OHALF>
__global__ __launch_bounds__(256) void k_spmm_x(
    const __half* __restrict__ X, const int* __restrict__ row_ptr,
    const int* __restrict__ csr_src, const float* __restrict__ nd,
    const float* __restrict__ bias, void* __restrict__ Y, int n) {
  constexpr int NSL = D / 32;       // feature slices
  constexpr int G = 8 / NSL;        // node groups per slice
  const int xcd = blockIdx.x & 7;
  const int j = blockIdx.x >> 3;    // block index within XCD
  const int s = xcd % NSL;
  const int g = xcd / NSL;
  const int npg = (n + G - 1) / G;
  const int vbeg = g * npg;
  const int vend = min(n, vbeg + npg);
  const int wave = (int)(threadIdx.x >> 6);
  const int lane = (int)(threadIdx.x & 63);
  const int sub = lane >> 4;        // edge slot 0..3
  const int fl = lane & 15;         // feature lane
  const int off = s * 32 + fl * 2;
  const __half* __restrict__ Xo = X + off;
  const int stride = SPMM_J * 4;

  for (int v = vbeg + j * 4 + wave; v < vend; v += stride) {
    float a0 = 0.f, a1 = 0.f;
    const int beg = row_ptr[v];
    const int end_ = row_ptr[v + 1];
    if (sub == 0) {   // self term
      union { unsigned u; __half2 h; } t;
      t.u = *reinterpret_cast<const unsigned*>(Xo + (size_t)v * D);
      float2 f = __half22float2(t.h);
      a0 = f.x; a1 = f.y;
    }
    for (int e = beg + sub; e < end_; e += 4) {
      int u = csr_src[e];
      union { unsigned uu; __half2 h; } t;
      t.uu = *reinterpret_cast<const unsigned*>(Xo + (size_t)u * D);
      float2 f = __half22float2(t.h);
      a0 += f.x; a1 += f.y;
    }
    a0 += __shfl_xor(a0, 16); a0 += __shfl_xor(a0, 32);
    a1 += __shfl_xor(a1, 16); a1 += __shfl_xor(a1, 32);
    if (sub == 0) {
      const float sc = nd[v];
      float o0 = sc * a0, o1 = sc * a1;
      if (BIAS) { o0 += bias[off]; o1 += bias[off + 1]; }
      if constexpr (OHALF) {
        *reinterpret_cast<__half2*>(reinterpret_cast<__half*>(Y) + (size_t)v * D + off) =
            __floats2half2_rn(o0, o1);
      } else {
        *reinterpret_cast<float2*>(reinterpret_cast<float*>(Y) + (size_t)v * D + off) =
            make_float2(o0, o1);
      }
    }
  }
}

// ---------------- pure-fp16 MFMA GEMM ----------------
template <int K, int NOUT, int BM, int WM, int WN, int MF, int NF,
          bool RELU, bool BIAS, bool NSOUT, bool OHALF>
__global__ __launch_bounds__(256) void k_gemm_h(
    const __half* __restrict__ A, const __half* __restrict__ Wt,
    const float* __restrict__ bias, const float* __restrict__ ns,
    void* __restrict__ C, int M) {
  constexpr int BN = WN * NF * 16;
  static_assert(BM == WM * MF * 16, "BM mismatch");
  static_assert(BN == NOUT, "BN must equal NOUT");
  constexpr int LDP = 40;  // 80B row stride -> bank stride 20 -> <=2-way (free), 16B aligned

  __shared__ __half As[BM][LDP];
  __shared__ __half Ws[BN][LDP];

  const int tid = threadIdx.x;
  const int bm = blockIdx.x * BM;
  const int lane = tid & 63;
  const int wave = tid >> 6;
  const int wmi = wave / WN;
  const int wni = wave % WN;
  const int rl = lane & 15;
  const int kg = lane >> 4;       // 0..3
  const int kb = kg * 8;

  f32x4 acc[MF][NF];
#pragma unroll
  for (int m = 0; m < MF; ++m)
#pragma unroll
    for (int n = 0; n < NF; ++n) acc[m][n] = (f32x4){0.f, 0.f, 0.f, 0.f};

  for (int kk = 0; kk < K; kk += 32) {
#pragma unroll
    for (int s0 = 0; s0 < BM * 4; s0 += 256) {
      int s = s0 + tid;
      int r = s >> 2, c8 = (s & 3) << 3;
      int grow = bm + r;
      ushort8v v = (ushort8v){0, 0, 0, 0, 0, 0, 0, 0};
      if (grow < M)
        v = *reinterpret_cast<const ushort8v*>(A + (size_t)grow * K + kk + c8);
      *reinterpret_cast<ushort8v*>(&As[r][c8]) = v;
    }
#pragma unroll
    for (int s0 = 0; s0 < BN * 4; s0 += 256) {
      int s = s0 + tid;
      int nn = s >> 2, k8 = (s & 3) << 3;
      *reinterpret_cast<ushort8v*>(&Ws[nn][k8]) =
          *reinterpret_cast<const ushort8v*>(Wt + (size_t)nn * K + kk + k8);
    }
    __syncthreads();

    f16x8 af[MF], bf[NF];
#pragma unroll
    for (int m = 0; m < MF; ++m) {
      const int r = wmi * MF * 16 + m * 16 + rl;
      af[m] = *reinterpret_cast<const f16x8*>(&As[r][kb]);
    }
#pragma unroll
    for (int n = 0; n < NF; ++n) {
      const int c = wni * NF * 16 + n * 16 + rl;
      bf[n] = *reinterpret_cast<const f16x8*>(&Ws[c][kb]);
    }
#pragma unroll
    for (int m = 0; m < MF; ++m)
#pragma unroll
      for (int n = 0; n < NF; ++n)
        acc[m][n] = __builtin_amdgcn_mfma_f32_16x16x32_f16(af[m], bf[n], acc[m][n], 0, 0, 0);
    __syncthreads();
  }

#pragma unroll
  for (int m = 0; m < MF; ++m) {
#pragma unroll
    for (int n = 0; n < NF; ++n) {
      const int col = wni * NF * 16 + n * 16 + rl;
      const float bb = BIAS ? bias[col] : 0.f;
      const int rowbase = bm + wmi * MF * 16 + m * 16 + kg * 4;
#pragma unroll
      for (int i = 0; i < 4; ++i) {
        int grow = rowbase + i;
        if (grow < M) {
          float val = acc[m][n][i] + bb;
          if (RELU) val = fmaxf(val, 0.f);
          if (NSOUT) val *= ns[grow];
          if constexpr (OHALF)
            reinterpret_cast<__half*>(C)[(size_t)grow * NOUT + col] = __float2half_rn(val);
          else
            reinterpret_cast<float*>(C)[(size_t)grow * NOUT + col] = val;
        }
      }
    }
  }
}

// ---------------- launch ----------------
extern "C" void kernel_launch(void* const* d_in, const int* in_sizes, int n_in,
                              void* d_out, int out_size, void* d_ws, size_t ws_size,
                              hipStream_t stream) {
  const float* feats = (const float*)d_in[0];
  const float* W1 = (const float*)d_in[1];
  const float* b1 = (const float*)d_in[2];
  const float* W2 = (const float*)d_in[3];
  const float* b2 = (const float*)d_in[4];
  const float* W3 = (const float*)d_in[5];
  const float* b3 = (const float*)d_in[6];
  const int* src = (const int*)d_in[7];
  const int* dst = (const int*)d_in[8];
  float* out = (float*)d_out;
  const int N = NODES;
  const int E = in_sizes[7];
  const int NB = (N + 255) / 256;          // scan blocks (196 <= 256)

  char* ws = (char*)d_ws;
  size_t off = 0;
  auto alloc = [&](size_t bytes) -> void* {
    void* p = ws + off;
    off += (bytes + 255) & ~(size_t)255;
    return p;
  };
  __half* w0h = (__half*)alloc((size_t)N * 256 * sizeof(__half));
  __half* w1r = (__half*)alloc((size_t)N * 256 * sizeof(__half));
  __half* w2r = (__half*)alloc((size_t)N * 256 * sizeof(__half));
  int* deg_in = (int*)alloc((size_t)N * sizeof(int));
  float* ns = (float*)alloc((size_t)N * sizeof(float));
  float* nd = (float*)alloc((size_t)N * sizeof(float));
  int* row_ptr = (int*)alloc((size_t)(N + 1) * sizeof(int));
  int* csr_src = (int*)alloc((size_t)E * sizeof(int));
  int* psum = (int*)alloc((size_t)NB * sizeof(int));
  unsigned* p_out = (unsigned*)alloc((size_t)SLICES * NPACK * sizeof(unsigned));
  unsigned* p_in = (unsigned*)alloc((size_t)SLICES * NPACK * sizeof(unsigned));
  unsigned* base_in = (unsigned*)alloc((size_t)SLICES * NPACK * sizeof(unsigned));
  __half* wt1 = (__half*)alloc((size_t)F_IN * F_H1 * sizeof(__half));
  __half* wt2 = (__half*)alloc((size_t)F_H1 * F_H2 * sizeof(__half));
  __half* wt3 = (__half*)alloc((size_t)F_H2 * F_OUT * sizeof(__half));
  (void)ws_size; (void)n_in; (void)out_size;

  // ---- weight transpose -> fp16 (tiny) ----
  hipLaunchKernelGGL(k_wprep_h, dim3((F_IN * F_H1 + 255) / 256), dim3(256), 0, stream,
                     W1, wt1, F_IN, F_H1);
  hipLaunchKernelGGL(k_wprep_h, dim3((F_H1 * F_H2 + 255) / 256), dim3(256), 0, stream,
                     W2, wt2, F_H1, F_H2);
  hipLaunchKernelGGL(k_wprep_h, dim3((F_H2 * F_OUT + 255) / 256), dim3(256), 0, stream,
                     W3, wt3, F_H2, F_OUT);

  // ---- graph preprocessing (no global atomics) ----
  hipLaunchKernelGGL(k_hist, dim3(SLICES * 2), dim3(512), 0, stream,
                     src, dst, p_out, p_in, E);
  hipLaunchKernelGGL(k_degnorm, dim3((NPACK + 255) / 256), dim3(256), 0, stream,
                     p_out, p_in, base_in, deg_in, ns, nd);
  hipLaunchKernelGGL(k_scan1, dim3(NB), dim3(256), 0, stream, deg_in, psum, N);
  hipLaunchKernelGGL(k_scan2, dim3(1), dim3(256), 0, stream, psum, NB);
  hipLaunchKernelGGL(k_scan3, dim3(NB), dim3(256), 0, stream, deg_in, psum, row_ptr, N);
  hipLaunchKernelGGL(k_scatter2, dim3(SLICES * 2), dim3(512), 0, stream,
                     src, dst, row_ptr, base_in, csr_src, E);

  // ---- prescale feats by ns -> fp16 ----
  hipLaunchKernelGGL(k_prescale_h, dim3((N * 32 + 255) / 256), dim3(256), 0, stream,
                     feats, ns, w2r, N * 32);

  const dim3 spmm_grid(8 * SPMM_J);

  // ---- layer 1: SpMM(d=128, XCD-sliced) -> fp16; GEMM 128->256 (+b1, relu, *ns) -> fp16
  hipLaunchKernelGGL((k_spmm_x<128, false, true>), spmm_grid, dim3(256), 0, stream,
                     w2r, row_ptr, csr_src, nd, nullptr, w1r, N);
  hipLaunchKernelGGL((k_gemm_h<128, 256, 64, 1, 4, 4, 4, true, true, true, true>),
                     dim3((N + 63) / 64), dim3(256), 0, stream,
                     w1r, wt1, b1, ns, w2r, N);

  // ---- layer 2: SpMM(d=256, XCD-sliced) -> fp16; GEMM 256->256 (+b2, relu, *ns) -> fp16
  hipLaunchKernelGGL((k_spmm_x<256, false, true>), spmm_grid, dim3(256), 0, stream,
                     w2r, row_ptr, csr_src, nd, nullptr, w0h, N);
  hipLaunchKernelGGL((k_gemm_h<256, 256, 64, 1, 4, 4, 4, true, true, true, true>),
                     dim3((N + 63) / 64), dim3(256), 0, stream,
                     w0h, wt2, b2, ns, w1r, N);

  // ---- layer 3: GEMM 256->64 (no act) -> fp16; SpMM(d=64, XCD-sliced) +b3 -> out f32
  hipLaunchKernelGGL((k_gemm_h<256, 64, 128, 4, 1, 2, 4, false, false, false, true>),
                     dim3((N + 127) / 128), dim3(256), 0, stream,
                     w1r, wt3, nullptr, nullptr, w2r, N);
  hipLaunchKernelGGL((k_spmm_x<64, true, false>), spmm_grid, dim3(256), 0, stream,
                     w2r, row_ptr, csr_src, nd, b3, out, N);
}

// Round 10
// 261.849 us; speedup vs baseline: 2.6575x; 2.6575x over previous
//
#include <hip/hip_runtime.h>
#include <hip/hip_fp16.h>
#include <stdint.h>

// ---------------- problem constants ----------------
#define NODES 50000
#define F_IN 128
#define F_H1 256
#define F_H2 256
#define F_OUT 64
#define SLICES 64            // edge slices for hist/scatter
#define NPACK (NODES / 2)    // packed ushort-pair bins (25000)
#define QPACK (NPACK / 4)    // bins per node-quarter (6250, 25 KB LDS per array)

using f32x4    = __attribute__((ext_vector_type(4))) float;
using f16x8    = __attribute__((ext_vector_type(8))) _Float16;   // 8 fp16 in 4 VGPRs
using ushort8v = __attribute__((ext_vector_type(8))) unsigned short;

// ---------------- atomic-free degree/CSR machinery ----------------
// k_hist2: block (s = b>>2, r = b&3) histograms edge-slice s for node quarter r.
// Single pass over edges; src and dst binned into separate 25 KB LDS arrays
// (packed ushort pairs). 256 blocks -> full CU coverage.
__global__ __launch_bounds__(512) void k_hist2(
    const int* __restrict__ src, const int* __restrict__ dst,
    unsigned* __restrict__ p_out, unsigned* __restrict__ p_in, int e) {
  __shared__ unsigned bo[QPACK];
  __shared__ unsigned bi[QPACK];
  const int s = blockIdx.x >> 2;
  const int r = blockIdx.x & 3;
  const int nlo = r * (NODES / 4);
  const int nhi = nlo + NODES / 4;
  const int plo = r * QPACK;
  const int per = (e + SLICES - 1) / SLICES;
  const int beg = s * per;
  const int end = min(e, beg + per);

  for (int j = threadIdx.x; j < QPACK; j += 512) { bo[j] = 0; bi[j] = 0; }
  __syncthreads();
  for (int i = beg + (int)threadIdx.x; i < end; i += 512) {
    int a = src[i];
    if (a >= nlo && a < nhi)
      atomicAdd(&bo[(a >> 1) - plo], 1u << ((a & 1) << 4));
    int d = dst[i];
    if (d >= nlo && d < nhi)
      atomicAdd(&bi[(d >> 1) - plo], 1u << ((d & 1) << 4));
  }
  __syncthreads();
  for (int j = threadIdx.x; j < QPACK; j += 512) {
    p_out[(size_t)s * NPACK + plo + j] = bo[j];
    p_in[(size_t)s * NPACK + plo + j] = bi[j];
  }
}

// k_degnorm: reduce partials -> degrees (+1 self-loop), fused rsqrt norms,
// and write per-slice exclusive prefix (scatter bases) for the dst direction.
__global__ __launch_bounds__(256) void k_degnorm(
    const unsigned* __restrict__ p_out, const unsigned* __restrict__ p_in,
    unsigned* __restrict__ base_in, int* __restrict__ deg_in,
    float* __restrict__ ns, float* __restrict__ nd) {
  int p = blockIdx.x * 256 + threadIdx.x;
  if (p >= NPACK) return;
  unsigned so = 0, si = 0;
#pragma unroll 4
  for (int s = 0; s < SLICES; ++s) {
    so += p_out[(size_t)s * NPACK + p];
    unsigned vi = p_in[(size_t)s * NPACK + p];
    base_in[(size_t)s * NPACK + p] = si;   // exclusive prefix across slices
    si += vi;
  }
  int o0 = (int)(so & 0xFFFFu) + 1, o1 = (int)(so >> 16) + 1;   // +1 self-loop
  int i0 = (int)(si & 0xFFFFu) + 1, i1 = (int)(si >> 16) + 1;
  int n0 = p * 2, n1 = n0 + 1;
  deg_in[n0] = i0; deg_in[n1] = i1;
  ns[n0] = rsqrtf((float)o0); ns[n1] = rsqrtf((float)o1);
  nd[n0] = rsqrtf((float)i0); nd[n1] = rsqrtf((float)i1);
}

// ---------------- parallel 3-phase exclusive scan over (deg_in - 1) ----------------
__global__ __launch_bounds__(256) void k_scan1(const int* __restrict__ deg_in,
                                               int* __restrict__ psum, int n) {
  int i = blockIdx.x * 256 + threadIdx.x;
  int v = (i < n) ? deg_in[i] - 1 : 0;
#pragma unroll
  for (int o = 1; o < 64; o <<= 1) v += __shfl_xor(v, o);
  __shared__ int ws[4];
  if ((threadIdx.x & 63) == 0) ws[threadIdx.x >> 6] = v;
  __syncthreads();
  if (threadIdx.x == 0) psum[blockIdx.x] = ws[0] + ws[1] + ws[2] + ws[3];
}

__global__ __launch_bounds__(256) void k_scan2(int* __restrict__ psum, int nb) {
  __shared__ int s[256];
  int t = threadIdx.x;
  int v = (t < nb) ? psum[t] : 0;
  s[t] = v;
  __syncthreads();
  for (int o = 1; o < 256; o <<= 1) {
    int u = (t >= o) ? s[t - o] : 0;
    __syncthreads();
    s[t] += u;
    __syncthreads();
  }
  if (t < nb) psum[t] = s[t] - v;   // exclusive
}

__global__ __launch_bounds__(256) void k_scan3(const int* __restrict__ deg_in,
                                               const int* __restrict__ psum,
                                               int* __restrict__ row_ptr, int n) {
  int i = blockIdx.x * 256 + threadIdx.x;
  int lane = threadIdx.x & 63;
  int w = threadIdx.x >> 6;
  int v = (i < n) ? deg_in[i] - 1 : 0;
  int x = v;
#pragma unroll
  for (int o = 1; o < 64; o <<= 1) {
    int u = __shfl_up(x, o);
    if (lane >= o) x += u;
  }
  __shared__ int wsum[4];
  if (lane == 63) wsum[w] = x;
  __syncthreads();
  int woff = 0;
#pragma unroll
  for (int j = 0; j < 4; ++j)
    if (j < w) woff += wsum[j];
  int excl = x - v + woff + psum[blockIdx.x];
  if (i < n) row_ptr[i] = excl;
  if (i == n - 1) row_ptr[n] = excl + v;
}

// k_scatter4: counting-sort scatter, zero global atomics; quarter-node blocks.
__global__ __launch_bounds__(512) void k_scatter4(
    const int* __restrict__ src, const int* __restrict__ dst,
    const int* __restrict__ row_ptr, const unsigned* __restrict__ base_in,
    int* __restrict__ csr_src, int e) {
  __shared__ unsigned cur[QPACK];
  const int s = blockIdx.x >> 2;
  const int r = blockIdx.x & 3;
  const int nlo = r * (NODES / 4);
  const int nhi = nlo + NODES / 4;
  const int plo = r * QPACK;
  const int per = (e + SLICES - 1) / SLICES;
  const int beg = s * per;
  const int end = min(e, beg + per);
  for (int j = threadIdx.x; j < QPACK; j += 512)
    cur[j] = base_in[(size_t)s * NPACK + plo + j];
  __syncthreads();
  for (int i = beg + (int)threadIdx.x; i < end; i += 512) {
    int d = dst[i];
    if (d >= nlo && d < nhi) {
      int sh = (d & 1) << 4;
      unsigned old = atomicAdd(&cur[(d >> 1) - plo], 1u << sh);
      int local = (int)((old >> sh) & 0xFFFFu);
      csr_src[row_ptr[d] + local] = src[i];
    }
  }
}

// ---------------- feats prescale -> fp16: Y = fp16(ns[row] * X), X:[n][128] ----------------
__global__ void k_prescale_h(const float* __restrict__ X, const float* __restrict__ ns,
                             __half* __restrict__ Y, int total4) {
  int i = blockIdx.x * blockDim.x + threadIdx.x;
  if (i < total4) {
    int row = i >> 5;                       // 32 float4 per 128-col row
    float s = ns[row];
    float4 v = reinterpret_cast<const float4*>(X)[i];
    __half2 h0 = __floats2half2_rn(v.x * s, v.y * s);
    __half2 h1 = __floats2half2_rn(v.z * s, v.w * s);
    union { struct { __half2 a, b; } h; uint2 u; } o;
    o.h.a = h0; o.h.b = h1;
    reinterpret_cast<uint2*>(Y)[i] = o.u;
  }
}

// ---------------- weight prep: W[K][NOUT] f32 -> Wt [NOUT][K] fp16 ----------------
__global__ void k_wprep_h(const float* __restrict__ W, __half* __restrict__ Wt,
                          int K, int NOUT) {
  int i = blockIdx.x * blockDim.x + threadIdx.x;
  if (i < K * NOUT) {
    int k = i / NOUT, n = i % NOUT;
    Wt[(size_t)n * K + k] = __float2half_rn(W[i]);
  }
}

// ---------------- fp16 gather helpers ----------------
struct u32x8s { uint4 a, b; };
template <int HPL> struct raw_t_sel;
template <> struct raw_t_sel<2> { using type = unsigned int; };
template <> struct raw_t_sel<4> { using type = uint2; };
template <> struct raw_t_sel<8> { using type = uint4; };
template <> struct raw_t_sel<16> { using type = u32x8s; };

template <int HPL>
__device__ __forceinline__ typename raw_t_sel<HPL>::type graw(const __half* p) {
  if constexpr (HPL == 16) {
    u32x8s r;
    r.a = *reinterpret_cast<const uint4*>(p);
    r.b = *reinterpret_cast<const uint4*>(p + 8);
    return r;
  } else {
    return *reinterpret_cast<const typename raw_t_sel<HPL>::type*>(p);
  }
}
__device__ __forceinline__ void acc_u32(float* acc, unsigned u) {
  union { unsigned u; __half2 h; } a; a.u = u;
  float2 f = __half22float2(a.h);
  acc[0] += f.x; acc[1] += f.y;
}
template <int HPL>
__device__ __forceinline__ void raw_acc(float* acc, typename raw_t_sel<HPL>::type r) {
  if constexpr (HPL == 16) {
    acc_u32(acc + 0, r.a.x);  acc_u32(acc + 2, r.a.y);
    acc_u32(acc + 4, r.a.z);  acc_u32(acc + 6, r.a.w);
    acc_u32(acc + 8, r.b.x);  acc_u32(acc + 10, r.b.y);
    acc_u32(acc + 12, r.b.z); acc_u32(acc + 14, r.b.w);
  } else if constexpr (HPL == 8) {
    acc_u32(acc + 0, r.x); acc_u32(acc + 2, r.y);
    acc_u32(acc + 4, r.z); acc_u32(acc + 6, r.w);
  } else if constexpr (HPL == 4) {
    acc_u32(acc + 0, r.x); acc_u32(acc + 2, r.y);
  } else {
    acc_u32(acc, r);
  }
}

// ---------------- SpMM (fp16 source): Y[v] = nd[v]*(X[v] + sum_{u->v} X[u]) (+bias)
// EPI edges per wave-iteration: lane = (sub-edge, feature-slot); butterfly
// shfl_xor combine at the end. OHALF: fp16 out, else f32.
template <int D, int EPI, bool BIAS, bool OHALF>
__global__ __launch_bounds__(256) void k_spmm_h(
    const __half* __restrict__ X, const int* __restrict__ row_ptr,
    const int* __restrict__ csr_src, const float* __restrict__ nd,
    const float* __restrict__ bias, void* __restrict__ Y, int n) {
  constexpr int LPN = 64 / EPI;    // lanes per edge-row
  constexpr int HPL = D / LPN;     // halves per lane
  static_assert(HPL >= 2 && HPL <= 16, "bad HPL");
  const int v = (blockIdx.x * blockDim.x + threadIdx.x) >> 6;
  const int lane = threadIdx.x & 63;
  if (v >= n) return;
  const int sub = lane / LPN;
  const int fl = lane % LPN;
  const int off = fl * HPL;
  const __half* __restrict__ Xo = X + off;

  float acc[HPL] = {};
  if (sub == 0) raw_acc<HPL>(acc, graw<HPL>(Xo + (size_t)v * D));   // self term

  const int beg = row_ptr[v];
  const int end = row_ptr[v + 1];
#pragma unroll 2
  for (int e = beg + sub; e < end; e += EPI) {
    int u = csr_src[e];
    raw_acc<HPL>(acc, graw<HPL>(Xo + (size_t)u * D));
  }

  // combine sub-edge partial sums (butterfly over the sub dimension)
#pragma unroll
  for (int o = LPN; o < 64; o <<= 1)
#pragma unroll
    for (int i = 0; i < HPL; ++i) acc[i] += __shfl_xor(acc[i], o);

  if (sub != 0) return;
  const float sc = nd[v];
  float o[HPL];
#pragma unroll
  for (int i = 0; i < HPL; ++i) {
    o[i] = sc * acc[i];
    if (BIAS) o[i] += bias[off + i];
  }

  if constexpr (OHALF) {
    __half* yp = reinterpret_cast<__half*>(Y) + (size_t)v * D + off;
    if constexpr (HPL == 16) {
      union { struct { __half2 a, b, c, d; } h; uint4 u; } p0, p1;
      p0.h.a = __floats2half2_rn(o[0], o[1]);
      p0.h.b = __floats2half2_rn(o[2], o[3]);
      p0.h.c = __floats2half2_rn(o[4], o[5]);
      p0.h.d = __floats2half2_rn(o[6], o[7]);
      p1.h.a = __floats2half2_rn(o[8], o[9]);
      p1.h.b = __floats2half2_rn(o[10], o[11]);
      p1.h.c = __floats2half2_rn(o[12], o[13]);
      p1.h.d = __floats2half2_rn(o[14], o[15]);
      *reinterpret_cast<uint4*>(yp) = p0.u;
      *reinterpret_cast<uint4*>(yp + 8) = p1.u;
    } else if constexpr (HPL == 8) {
      union { struct { __half2 a, b, c, d; } h; uint4 u; } pk;
      pk.h.a = __floats2half2_rn(o[0], o[1]);
      pk.h.b = __floats2half2_rn(o[2], o[3]);
      pk.h.c = __floats2half2_rn(o[4], o[5]);
      pk.h.d = __floats2half2_rn(o[6], o[7]);
      *reinterpret_cast<uint4*>(yp) = pk.u;
    } else if constexpr (HPL == 4) {
      union { struct { __half2 a, b; } h; uint2 u; } pk;
      pk.h.a = __floats2half2_rn(o[0], o[1]);
      pk.h.b = __floats2half2_rn(o[2], o[3]);
      *reinterpret_cast<uint2*>(yp) = pk.u;
    } else {
      *reinterpret_cast<__half2*>(yp) = __floats2half2_rn(o[0], o[1]);
    }
  } else {
    float* yp = reinterpret_cast<float*>(Y) + (size_t)v * D + off;
    if constexpr (HPL == 8) {
      *reinterpret_cast<float4*>(yp) = make_float4(o[0], o[1], o[2], o[3]);
      *reinterpret_cast<float4*>(yp + 4) = make_float4(o[4], o[5], o[6], o[7]);
    } else if constexpr (HPL == 4) {
      *reinterpret_cast<float4*>(yp) = make_float4(o[0], o[1], o[2], o[3]);
    } else {
      *reinterpret_cast<float2*>(yp) = make_float2(o[0], o[1]);
    }
  }
}

// ---------------- pure-fp16 MFMA GEMM ----------------
template <int K, int NOUT, int BM, int WM, int WN, int MF, int NF,
          bool RELU, bool BIAS, bool NSOUT, bool OHALF>
__global__ __launch_bounds__(256) void k_gemm_h(
    const __half* __restrict__ A, const __half* __restrict__ Wt,
    const float* __restrict__ bias, const float* __restrict__ ns,
    void* __restrict__ C, int M) {
  constexpr int BN = WN * NF * 16;
  static_assert(BM == WM * MF * 16, "BM mismatch");
  static_assert(BN == NOUT, "BN must equal NOUT");
  constexpr int LDP = 40;  // 80B row stride -> bank stride 20 -> <=2-way (free), 16B aligned

  __shared__ __half As[BM][LDP];
  __shared__ __half Ws[BN][LDP];

  const int tid = threadIdx.x;
  const int bm = blockIdx.x * BM;
  const int lane = tid & 63;
  const int wave = tid >> 6;
  const int wmi = wave / WN;
  const int wni = wave % WN;
  const int rl = lane & 15;
  const int kg = lane >> 4;       // 0..3
  const int kb = kg * 8;

  f32x4 acc[MF][NF];
#pragma unroll
  for (int m = 0; m < MF; ++m)
#pragma unroll
    for (int n = 0; n < NF; ++n) acc[m][n] = (f32x4){0.f, 0.f, 0.f, 0.f};

  for (int kk = 0; kk < K; kk += 32) {
#pragma unroll
    for (int s0 = 0; s0 < BM * 4; s0 += 256) {
      int s = s0 + tid;
      int r = s >> 2, c8 = (s & 3) << 3;
      int grow = bm + r;
      ushort8v v = (ushort8v){0, 0, 0, 0, 0, 0, 0, 0};
      if (grow < M)
        v = *reinterpret_cast<const ushort8v*>(A + (size_t)grow * K + kk + c8);
      *reinterpret_cast<ushort8v*>(&As[r][c8]) = v;
    }
#pragma unroll
    for (int s0 = 0; s0 < BN * 4; s0 += 256) {
      int s = s0 + tid;
      int nn = s >> 2, k8 = (s & 3) << 3;
      *reinterpret_cast<ushort8v*>(&Ws[nn][k8]) =
          *reinterpret_cast<const ushort8v*>(Wt + (size_t)nn * K + kk + k8);
    }
    __syncthreads();

    f16x8 af[MF], bf[NF];
#pragma unroll
    for (int m = 0; m < MF; ++m) {
      const int r = wmi * MF * 16 + m * 16 + rl;
      af[m] = *reinterpret_cast<const f16x8*>(&As[r][kb]);
    }
#pragma unroll
    for (int n = 0; n < NF; ++n) {
      const int c = wni * NF * 16 + n * 16 + rl;
      bf[n] = *reinterpret_cast<const f16x8*>(&Ws[c][kb]);
    }
#pragma unroll
    for (int m = 0; m < MF; ++m)
#pragma unroll
      for (int n = 0; n < NF; ++n)
        acc[m][n] = __builtin_amdgcn_mfma_f32_16x16x32_f16(af[m], bf[n], acc[m][n], 0, 0, 0);
    __syncthreads();
  }

#pragma unroll
  for (int m = 0; m < MF; ++m) {
#pragma unroll
    for (int n = 0; n < NF; ++n) {
      const int col = wni * NF * 16 + n * 16 + rl;
      const float bb = BIAS ? bias[col] : 0.f;
      const int rowbase = bm + wmi * MF * 16 + m * 16 + kg * 4;
#pragma unroll
      for (int i = 0; i < 4; ++i) {
        int grow = rowbase + i;
        if (grow < M) {
          float val = acc[m][n][i] + bb;
          if (RELU) val = fmaxf(val, 0.f);
          if (NSOUT) val *= ns[grow];
          if constexpr (OHALF)
            reinterpret_cast<__half*>(C)[(size_t)grow * NOUT + col] = __float2half_rn(val);
          else
            reinterpret_cast<float*>(C)[(size_t)grow * NOUT + col] = val;
        }
      }
    }
  }
}

// ---------------- launch ----------------
extern "C" void kernel_launch(void* const* d_in, const int* in_sizes, int n_in,
                              void* d_out, int out_size, void* d_ws, size_t ws_size,
                              hipStream_t stream) {
  const float* feats = (const float*)d_in[0];
  const float* W1 = (const float*)d_in[1];
  const float* b1 = (const float*)d_in[2];
  const float* W2 = (const float*)d_in[3];
  const float* b2 = (const float*)d_in[4];
  const float* W3 = (const float*)d_in[5];
  const float* b3 = (const float*)d_in[6];
  const int* src = (const int*)d_in[7];
  const int* dst = (const int*)d_in[8];
  float* out = (float*)d_out;
  const int N = NODES;
  const int E = in_sizes[7];
  const int NB = (N + 255) / 256;          // scan blocks (196 <= 256)

  char* ws = (char*)d_ws;
  size_t off = 0;
  auto alloc = [&](size_t bytes) -> void* {
    void* p = ws + off;
    off += (bytes + 255) & ~(size_t)255;
    return p;
  };
  __half* w0h = (__half*)alloc((size_t)N * 256 * sizeof(__half));
  __half* w1r = (__half*)alloc((size_t)N * 256 * sizeof(__half));
  __half* w2r = (__half*)alloc((size_t)N * 256 * sizeof(__half));
  int* deg_in = (int*)alloc((size_t)N * sizeof(int));
  float* ns = (float*)alloc((size_t)N * sizeof(float));
  float* nd = (float*)alloc((size_t)N * sizeof(float));
  int* row_ptr = (int*)alloc((size_t)(N + 1) * sizeof(int));
  int* csr_src = (int*)alloc((size_t)E * sizeof(int));
  int* psum = (int*)alloc((size_t)NB * sizeof(int));
  unsigned* p_out = (unsigned*)alloc((size_t)SLICES * NPACK * sizeof(unsigned));
  unsigned* p_in = (unsigned*)alloc((size_t)SLICES * NPACK * sizeof(unsigned));
  unsigned* base_in = (unsigned*)alloc((size_t)SLICES * NPACK * sizeof(unsigned));
  __half* wt1 = (__half*)alloc((size_t)F_IN * F_H1 * sizeof(__half));
  __half* wt2 = (__half*)alloc((size_t)F_H1 * F_H2 * sizeof(__half));
  __half* wt3 = (__half*)alloc((size_t)F_H2 * F_OUT * sizeof(__half));
  (void)ws_size; (void)n_in; (void)out_size;

  // ---- weight transpose -> fp16 (tiny) ----
  hipLaunchKernelGGL(k_wprep_h, dim3((F_IN * F_H1 + 255) / 256), dim3(256), 0, stream,
                     W1, wt1, F_IN, F_H1);
  hipLaunchKernelGGL(k_wprep_h, dim3((F_H1 * F_H2 + 255) / 256), dim3(256), 0, stream,
                     W2, wt2, F_H1, F_H2);
  hipLaunchKernelGGL(k_wprep_h, dim3((F_H2 * F_OUT + 255) / 256), dim3(256), 0, stream,
                     W3, wt3, F_H2, F_OUT);

  // ---- graph preprocessing (no global atomics; 256-block single-pass hist) ----
  hipLaunchKernelGGL(k_hist2, dim3(SLICES * 4), dim3(512), 0, stream,
                     src, dst, p_out, p_in, E);
  hipLaunchKernelGGL(k_degnorm, dim3((NPACK + 255) / 256), dim3(256), 0, stream,
                     p_out, p_in, base_in, deg_in, ns, nd);
  hipLaunchKernelGGL(k_scan1, dim3(NB), dim3(256), 0, stream, deg_in, psum, N);
  hipLaunchKernelGGL(k_scan2, dim3(1), dim3(256), 0, stream, psum, NB);
  hipLaunchKernelGGL(k_scan3, dim3(NB), dim3(256), 0, stream, deg_in, psum, row_ptr, N);
  hipLaunchKernelGGL(k_scatter4, dim3(SLICES * 4), dim3(512), 0, stream,
                     src, dst, row_ptr, base_in, csr_src, E);

  // ---- prescale feats by ns -> fp16 ----
  hipLaunchKernelGGL(k_prescale_h, dim3((N * 32 + 255) / 256), dim3(256), 0, stream,
                     feats, ns, w2r, N * 32);

  auto grid_w = [](int waves) { return dim3((waves + 3) / 4); };  // 4 waves/block

  // ---- layer 1: SpMM(d=128, EPI=8) -> fp16; GEMM 128->256 (+b1, relu, *ns) -> fp16
  hipLaunchKernelGGL((k_spmm_h<128, 8, false, true>), grid_w(N), dim3(256), 0, stream,
                     w2r, row_ptr, csr_src, nd, nullptr, w1r, N);
  hipLaunchKernelGGL((k_gemm_h<128, 256, 64, 1, 4, 4, 4, true, true, true, true>),
                     dim3((N + 63) / 64), dim3(256), 0, stream,
                     w1r, wt1, b1, ns, w2r, N);

  // ---- layer 2: SpMM(d=256, EPI=4) -> fp16; GEMM 256->256 (+b2, relu, *ns) -> fp16
  hipLaunchKernelGGL((k_spmm_h<256, 4, false, true>), grid_w(N), dim3(256), 0, stream,
                     w2r, row_ptr, csr_src, nd, nullptr, w0h, N);
  hipLaunchKernelGGL((k_gemm_h<256, 256, 64, 1, 4, 4, 4, true, true, true, true>),
                     dim3((N + 63) / 64), dim3(256), 0, stream,
                     w0h, wt2, b2, ns, w1r, N);

  // ---- layer 3: GEMM 256->64 (no act) -> fp16; SpMM(d=64, EPI=8) +b3 -> out f32
  hipLaunchKernelGGL((k_gemm_h<256, 64, 128, 4, 1, 2, 4, false, false, false, true>),
                     dim3((N + 127) / 128), dim3(256), 0, stream,
                     w1r, wt3, nullptr, nullptr, w2r, N);
  hipLaunchKernelGGL((k_spmm_h<64, 8, true, false>), grid_w(N), dim3(256), 0, stream,
                     w2r, row_ptr, csr_src, nd, b3, out, N);
}